// Round 7
// baseline (402.426 us; speedup 1.0000x reference)
//
#include <hip/hip_runtime.h>
#include <stdint.h>

// out[n,o] = sum_{d,i} q[n,d] x[n,i] W1[d,i,o] + (q @ b1)[n,o]
// GEMM M=4096 N=256 K=16384 (k = d*256 + i), fp16 MFMA 32x32x16, fp32 accum.
//
// ROUND 7: cut W L2-traffic (the binding resource). R6 showed per-XCD L2 at
// ~2.1 TB/s effective ceiling under same-line sharing; duration tracked W
// traffic = (4096/Mtile)*8MB across rounds. New shape: Mtile=128 x Ntile=32,
// grid 256 = 32 mb x 8 nc (nc = bid&7 XCD-affine), ONE 1024-thread block per
// CU (16 waves = 4/SIMD). Each wave computes the FULL 128x32 tile for 4 of
// the 64 d's (acc = 4 x f32x16), load:MFMA = 1:4, W-ring depth 4 (~2000 cy
// coverage). d-reduction: 16-way in-LDS at the end (144 KB, epilogue-only).
// W traffic: 256 MB total = 32 MB/XCD (~15 us at contended-L2 rate) vs MFMA
// floor 13.7 us/SIMD -> balanced. Bias q@b1 folded into wave 15's acc.

typedef _Float16 f16;
typedef f16 f16x8 __attribute__((ext_vector_type(8)));
typedef float f32x16 __attribute__((ext_vector_type(16)));

#define QDIM 64

// one fp32-float8 -> f16x8
#define XFRAG(DST, PTR)                                      \
  do {                                                       \
    float4 a_ = *(const float4*)(PTR);                       \
    float4 b_ = *(const float4*)((PTR) + 4);                 \
    f16x8 h_;                                                \
    h_[0] = (f16)a_.x; h_[1] = (f16)a_.y; h_[2] = (f16)a_.z; \
    h_[3] = (f16)a_.w; h_[4] = (f16)b_.x; h_[5] = (f16)b_.y; \
    h_[6] = (f16)b_.z; h_[7] = (f16)b_.w;                    \
    DST = h_;                                                \
  } while (0)

// ---------------- prep (unchanged from R6 — layouts verified passing) -------
// Wt layout (8 MB):  byte = ((nc*64 + d)*16 + ic)*1024 + hf*512 + c*16 + j*2
//   <- W1[d][ic*16 + hf*8 + j][nc*32 + c]      (B-frag lane-linear, 1KB chunks)
// Xt layout (2 MB):  byte = ((mb64*16 + ic)*2 + hf)*1024 + row*16 + j*2
//   <- x[mb64*64 + row][ic*16 + hf*8 + j]      (A-frag lane-linear, 64-row tiles)
// Bt layout (32 KB): byte = ((nc*4 + kc)*2 + hf)*512 + c*16 + j*2
//   <- b1[kc*16 + hf*8 + j][nc*32 + c]
// grid 577: [0,512) W | [512,576) Xt | 576 Bt
__global__ __launch_bounds__(256) void prep(const float* __restrict__ W,
                                            const float* __restrict__ B1,
                                            const float* __restrict__ X,
                                            f16* __restrict__ Wt,
                                            f16* __restrict__ Xt,
                                            f16* __restrict__ Bt) {
  const int b = blockIdx.x, t = threadIdx.x;
  if (b < 512) {
    const int d = b >> 3, grp = b & 7;
    const int ibL = t >> 6;           // 0..3
    const int ib = (grp << 2) + ibL;  // i = ib*8 + j
    const int o0 = (t & 63) << 2;     // 4 consecutive o per lane
    const int ic = ib >> 1, hb = ib & 1;
    float v[32];
#pragma unroll
    for (int j = 0; j < 8; ++j) {
      float4 f = *(const float4*)(W + ((size_t)d * 256 + (ib << 3) + j) * 256 + o0);
      v[j * 4 + 0] = f.x; v[j * 4 + 1] = f.y;
      v[j * 4 + 2] = f.z; v[j * 4 + 3] = f.w;
    }
#pragma unroll
    for (int oo = 0; oo < 4; ++oo) {
      const int o = o0 + oo, ncb = o >> 5, c = o & 31;
      f16x8 h;
#pragma unroll
      for (int j = 0; j < 8; ++j) h[j] = (f16)v[j * 4 + oo];
      *(f16x8*)((char*)Wt + ((((size_t)ncb * 64 + d) * 16 + ic) << 10) +
                (hb << 9) + (c << 4)) = h;
    }
  } else if (b < 576) {
    const int mb = b - 512;  // 64-row tiles
#pragma unroll
    for (int rep = 0; rep < 8; ++rep) {
      const int u = (rep << 8) + t;          // 0..2047
      const int row = u & 63, ish = u >> 6;  // ish 0..31, i = ish*8 + j
      const float* src = X + ((size_t)((mb << 6) + row)) * 256 + (ish << 3);
      f16x8 h;
      XFRAG(h, src);
      *(f16x8*)((char*)Xt + ((((size_t)mb * 16 + (ish >> 1)) * 2 + (ish & 1)) << 10) +
                (row << 4)) = h;
    }
  } else {
#pragma unroll
    for (int kb = 0; kb < 8; ++kb) {  // k = kb*8 + j
      const float* src = B1 + ((size_t)kb << 3) * 256 + t;
      f16x8 h;
#pragma unroll
      for (int j = 0; j < 8; ++j) h[j] = (f16)src[(size_t)j << 8];
      *(f16x8*)((char*)Bt + (((size_t)(t >> 5) * 4 + (kb >> 1)) << 10) +
                ((kb & 1) << 9) + ((t & 31) << 4)) = h;
    }
  }
}

// ---- main: 256 blocks = 32 mb-tiles (128 rows) x 8 col-tiles (32 cols) ----
// 1024 threads = 16 waves; wave w owns d-range [w*4, w*4+4), computes the full
// 128x32 tile for those d's. 16-way d-reduction in LDS at the end.
__global__ __launch_bounds__(1024, 4) void mlp_main(const float* __restrict__ Q,
                                                    const f16* __restrict__ Wt,
                                                    const f16* __restrict__ Xt,
                                                    const f16* __restrict__ Bt,
                                                    float* __restrict__ out) {
  __shared__ __align__(16) float red[8][128][36];  // 144 KB, epilogue only

  const int bid = blockIdx.x;
  const int nc = bid & 7;   // XCD-affine column tile
  const int mb = bid >> 3;  // 0..31, 128-row tile
  const int t = threadIdx.x;
  const int w = t >> 6;     // 0..15, d-range [w*4, w*4+4)
  const int l = t & 63;
  const int l31 = l & 31;
  const int hf = l >> 5;

  // per-lane W base: chunk (dd, ic) at + (dd*16 + ic)*1024
  const char* wl = (const char*)Wt + (((size_t)(nc * 64 + (w << 2))) << 14) +
                   (hf << 9) + (l31 << 4);
  // x frag (mt, ic): tile64 = mb*2 + (mt>>1), row = (mt&1)*32 + l31
  const char* xB = (const char*)Xt + ((size_t)(mb << 1) << 15) + (hf << 10) +
                   ((size_t)l31 << 4);
  // per-mt extra offsets: (mt>>1)*32768 + (mt&1)*512

  // q scalars: q[mb*128 + mt*32 + l31][w*4 + dd]  (one float4 per mt)
  f16 qr[4][4];
#pragma unroll
  for (int mt = 0; mt < 4; ++mt) {
    float4 qv = *(const float4*)(Q + (size_t)((mb << 7) + (mt << 5) + l31) * QDIM +
                                 (w << 2));
    qr[mt][0] = (f16)qv.x; qr[mt][1] = (f16)qv.y;
    qr[mt][2] = (f16)qv.z; qr[mt][3] = (f16)qv.w;
  }

  f32x16 acc[4];
#pragma unroll
  for (int mt = 0; mt < 4; ++mt)
#pragma unroll
    for (int r = 0; r < 16; ++r) acc[mt][r] = 0.f;

  f16x8 Wr[4], xfA[4];

  // ic-stagger: same-XCD blocks (mb 0..31) start at 8 different phases
  const int icoff = (mb & 7) << 1;

#pragma unroll
  for (int dd = 0; dd < 4; ++dd)
    Wr[dd] = *(const f16x8*)(wl + (((size_t)((dd << 4) + icoff)) << 10));
#pragma unroll
  for (int mt = 0; mt < 4; ++mt)
    xfA[mt] = *(const f16x8*)(xB + ((mt >> 1) << 15) + ((mt & 1) << 9) +
                              ((size_t)icoff << 11));

  for (int s = 0; s < 16; ++s) {
    const int icn = (icoff + s + 1) & 15;  // s==15: wraps -> dead reloads
#pragma unroll
    for (int dd = 0; dd < 4; ++dd) {
      f16x8 wf = Wr[dd];
      Wr[dd] = *(const f16x8*)(wl + (((size_t)((dd << 4) + icn)) << 10));
#pragma unroll
      for (int mt = 0; mt < 4; ++mt) {
        f16x8 a = xfA[mt] * qr[mt][dd];
        acc[mt] = __builtin_amdgcn_mfma_f32_32x32x16_f16(a, wf, acc[mt], 0, 0, 0);
      }
    }
    // reload x frags for next ic (after last use this iteration)
#pragma unroll
    for (int mt = 0; mt < 4; ++mt)
      xfA[mt] = *(const f16x8*)(xB + ((mt >> 1) << 15) + ((mt & 1) << 9) +
                                ((size_t)icn << 11));
  }

  // bias (wave 15 only): 4 chunks over QDIM, A = q-frag, B = Bt
  if (w == 15) {
#pragma unroll
    for (int kc = 0; kc < 4; ++kc) {
      f16x8 bf = *(const f16x8*)((const char*)Bt +
          (((size_t)nc * 4 + kc) << 10) + (hf << 9) + (l31 << 4));
#pragma unroll
      for (int mt = 0; mt < 4; ++mt) {
        f16x8 qf;
        XFRAG(qf, Q + (size_t)((mb << 7) + (mt << 5) + l31) * QDIM +
                  (kc << 4) + (hf << 3));
        acc[mt] = __builtin_amdgcn_mfma_f32_32x32x16_f16(qf, bf, acc[mt], 0, 0, 0);
      }
    }
  }

  // ---- 16-way d-reduction in LDS ----
  // C/D (32x32): col = lane&31, row = (reg&3) + 8*(reg>>2) + 4*(lane>>5)
  if (w < 8) {
#pragma unroll
    for (int mt = 0; mt < 4; ++mt)
#pragma unroll
      for (int r = 0; r < 16; ++r) {
        const int row = (mt << 5) + (r & 3) + ((r >> 2) << 3) + (hf << 2);
        red[w][row][l31] = acc[mt][r];
      }
  }
  __syncthreads();
  if (w >= 8) {
#pragma unroll
    for (int mt = 0; mt < 4; ++mt)
#pragma unroll
      for (int r = 0; r < 16; ++r) {
        const int row = (mt << 5) + (r & 3) + ((r >> 2) << 3) + (hf << 2);
        red[w - 8][row][l31] += acc[mt][r];
      }
  }
  __syncthreads();

  // final: 1024 threads x 4 outputs (float4), sum the 8 regions
  const int r = t >> 3;         // 0..127
  const int c0 = (t & 7) << 2;  // 0,4,...,28
  float4 s4 = {0.f, 0.f, 0.f, 0.f};
#pragma unroll
  for (int j = 0; j < 8; ++j) {
    float4 v = *(const float4*)(&red[j][r][c0]);
    s4.x += v.x; s4.y += v.y; s4.z += v.z; s4.w += v.w;
  }
  *(float4*)(out + ((size_t)((mb << 7) + r)) * 256 + (nc << 5) + c0) = s4;
}

extern "C" void kernel_launch(void* const* d_in, const int* in_sizes, int n_in,
                              void* d_out, int out_size, void* d_ws, size_t ws_size,
                              hipStream_t stream) {
  (void)in_sizes; (void)n_in; (void)out_size; (void)ws_size;
  const float* x  = (const float*)d_in[0];   // [4096,256]
  const float* q  = (const float*)d_in[1];   // [4096,64]
  const float* W1 = (const float*)d_in[2];   // [64,256,256]
  const float* b1 = (const float*)d_in[3];   // [64,256]
  float* out = (float*)d_out;                // [4096,256] fp32

  // ws: Wt 8 MB | Bt 32 KB | Xt 2 MB  (~10.03 MB)
  f16* Wt = (f16*)d_ws;
  f16* Bt = (f16*)((char*)d_ws + ((size_t)8 << 20));
  f16* Xt = (f16*)((char*)d_ws + ((size_t)8 << 20) + 32768);

  prep<<<577, 256, 0, stream>>>(W1, b1, x, Wt, Xt, Bt);
  mlp_main<<<256, 1024, 0, stream>>>(q, Wt, Xt, Bt, out);
}

// Round 8
// 120.079 us; speedup vs baseline: 3.3514x; 3.3514x over previous
//
#include <hip/hip_runtime.h>
#include <stdint.h>

// out[n,o] = sum_{d,i} q[n,d] x[n,i] W1[d,i,o] + (q @ b1)[n,o]
// GEMM M=4096 N=256 K=16384 (k = d*256 + i), fp16 MFMA 32x32x16, fp32 accum.
//
// ROUND 8: R7 concept (tall wave tile -> load:MFMA = 1:4, W traffic 256 MB)
// with a spill-proof configuration. R7's failure was the unified VGPR/AGPR
// budget: launch_bounds(1024,4) -> 128 unified regs vs ~150 needed -> scratch
// (FETCH 1.12 GB was spill traffic). Now: 512-thread blocks (8 waves), grid
// 256 = 32 mb x 8 nc (1 block/CU), wave = 128 rows x 32 cols x 8 d's, acc =
// 4 x f32x16 = 64 AGPR + ~105 arch regs, launch_bounds(512,2) -> 256-reg
// budget, no spill. Full K in-block; two-phase LDS d-reduction (74 KB).
// W ring depth 8 over d (static idx), x double-buffered per-ic. ic-stagger
// (mb&7)*2. Bias q@b1 folded into wave 7. MFMA floor 13.65 us/SIMD.

typedef _Float16 f16;
typedef f16 f16x8 __attribute__((ext_vector_type(8)));
typedef float f32x16 __attribute__((ext_vector_type(16)));

#define QDIM 64

// one fp32-float8 -> f16x8
#define XFRAG(DST, PTR)                                      \
  do {                                                       \
    float4 a_ = *(const float4*)(PTR);                       \
    float4 b_ = *(const float4*)((PTR) + 4);                 \
    f16x8 h_;                                                \
    h_[0] = (f16)a_.x; h_[1] = (f16)a_.y; h_[2] = (f16)a_.z; \
    h_[3] = (f16)a_.w; h_[4] = (f16)b_.x; h_[5] = (f16)b_.y; \
    h_[6] = (f16)b_.z; h_[7] = (f16)b_.w;                    \
    DST = h_;                                                \
  } while (0)

// ---------------- prep (byte-identical to R6/R7 — layouts verified) --------
// Wt layout (8 MB):  byte = ((nc*64 + d)*16 + ic)*1024 + hf*512 + c*16 + j*2
//   <- W1[d][ic*16 + hf*8 + j][nc*32 + c]      (B-frag lane-linear, 1KB chunks)
// Xt layout (2 MB):  byte = ((mb64*16 + ic)*2 + hf)*1024 + row*16 + j*2
//   <- x[mb64*64 + row][ic*16 + hf*8 + j]      (A-frag lane-linear, 64-row tiles)
// Bt layout (32 KB): byte = ((nc*4 + kc)*2 + hf)*512 + c*16 + j*2
//   <- b1[kc*16 + hf*8 + j][nc*32 + c]
// grid 577: [0,512) W | [512,576) Xt | 576 Bt
__global__ __launch_bounds__(256) void prep(const float* __restrict__ W,
                                            const float* __restrict__ B1,
                                            const float* __restrict__ X,
                                            f16* __restrict__ Wt,
                                            f16* __restrict__ Xt,
                                            f16* __restrict__ Bt) {
  const int b = blockIdx.x, t = threadIdx.x;
  if (b < 512) {
    const int d = b >> 3, grp = b & 7;
    const int ibL = t >> 6;           // 0..3
    const int ib = (grp << 2) + ibL;  // i = ib*8 + j
    const int o0 = (t & 63) << 2;     // 4 consecutive o per lane
    const int ic = ib >> 1, hb = ib & 1;
    float v[32];
#pragma unroll
    for (int j = 0; j < 8; ++j) {
      float4 f = *(const float4*)(W + ((size_t)d * 256 + (ib << 3) + j) * 256 + o0);
      v[j * 4 + 0] = f.x; v[j * 4 + 1] = f.y;
      v[j * 4 + 2] = f.z; v[j * 4 + 3] = f.w;
    }
#pragma unroll
    for (int oo = 0; oo < 4; ++oo) {
      const int o = o0 + oo, ncb = o >> 5, c = o & 31;
      f16x8 h;
#pragma unroll
      for (int j = 0; j < 8; ++j) h[j] = (f16)v[j * 4 + oo];
      *(f16x8*)((char*)Wt + ((((size_t)ncb * 64 + d) * 16 + ic) << 10) +
                (hb << 9) + (c << 4)) = h;
    }
  } else if (b < 576) {
    const int mb = b - 512;  // 64-row tiles
#pragma unroll
    for (int rep = 0; rep < 8; ++rep) {
      const int u = (rep << 8) + t;          // 0..2047
      const int row = u & 63, ish = u >> 6;  // ish 0..31, i = ish*8 + j
      const float* src = X + ((size_t)((mb << 6) + row)) * 256 + (ish << 3);
      f16x8 h;
      XFRAG(h, src);
      *(f16x8*)((char*)Xt + ((((size_t)mb * 16 + (ish >> 1)) * 2 + (ish & 1)) << 10) +
                (row << 4)) = h;
    }
  } else {
#pragma unroll
    for (int kb = 0; kb < 8; ++kb) {  // k = kb*8 + j
      const float* src = B1 + ((size_t)kb << 3) * 256 + t;
      f16x8 h;
#pragma unroll
      for (int j = 0; j < 8; ++j) h[j] = (f16)src[(size_t)j << 8];
      *(f16x8*)((char*)Bt + (((size_t)(t >> 5) * 4 + (kb >> 1)) << 10) +
                ((kb & 1) << 9) + ((t & 31) << 4)) = h;
    }
  }
}

// load the 4 x frags (mt=0..3) for one ic
#define LOADX4(D, IC)                                                        \
  do {                                                                       \
    _Pragma("unroll")                                                        \
    for (int mt_ = 0; mt_ < 4; ++mt_)                                        \
      D[mt_] = *(const f16x8*)(xB + ((mt_ >> 1) << 15) + ((mt_ & 1) << 9) +  \
                               ((size_t)(IC) << 11));                        \
  } while (0)

// consume the 8-d ring for one ic (frags already in Wr), prefetch ic ICN.
#define DPASS(XF, ICN)                                                       \
  do {                                                                       \
    _Pragma("unroll")                                                        \
    for (int dd_ = 0; dd_ < 8; ++dd_) {                                      \
      f16x8 wf_ = Wr[dd_];                                                   \
      Wr[dd_] = *(const f16x8*)(wl + (((size_t)((dd_ << 4) + (ICN))) << 10));\
      _Pragma("unroll")                                                      \
      for (int mt_ = 0; mt_ < 4; ++mt_) {                                    \
        f16x8 a_ = XF[mt_] * qr[mt_][dd_];                                   \
        acc[mt_] = __builtin_amdgcn_mfma_f32_32x32x16_f16(a_, wf_,           \
                                                          acc[mt_], 0, 0, 0);\
      }                                                                      \
    }                                                                        \
  } while (0)

// ---- main: 256 blocks = 32 mb-tiles (128 rows) x 8 col-tiles (32 cols) ----
// 512 threads = 8 waves; wave w owns d-range [w*8, w*8+8), computes the full
// 128x32 tile for those d's. Two-phase LDS d-reduction at the end.
__global__ __launch_bounds__(512, 2) void mlp_main(const float* __restrict__ Q,
                                                   const f16* __restrict__ Wt,
                                                   const f16* __restrict__ Xt,
                                                   const f16* __restrict__ Bt,
                                                   float* __restrict__ out) {
  __shared__ __align__(16) float red[4][128][36];  // 73.7 KB, epilogue only

  const int bid = blockIdx.x;
  const int nc = bid & 7;   // XCD-affine column tile
  const int mb = bid >> 3;  // 0..31, 128-row tile
  const int t = threadIdx.x;
  const int w = t >> 6;     // 0..7, d-range [w*8, w*8+8)
  const int l = t & 63;
  const int l31 = l & 31;
  const int hf = l >> 5;

  // per-lane W base: chunk (dd, ic) at + (dd*16 + ic)*1024
  const char* wl = (const char*)Wt + (((size_t)(nc * 64 + (w << 3))) << 14) +
                   (hf << 9) + (l31 << 4);
  // x frag (mt, ic): tile64 = mb*2 + (mt>>1), row = (mt&1)*32 + l31
  const char* xB = (const char*)Xt + ((size_t)(mb << 1) << 15) + (hf << 10) +
                   ((size_t)l31 << 4);

  // q scalars: q[mb*128 + mt*32 + l31][w*8 + dd]  (float8 per mt)
  f16 qr[4][8];
#pragma unroll
  for (int mt = 0; mt < 4; ++mt) {
    const float* qp = Q + (size_t)((mb << 7) + (mt << 5) + l31) * QDIM + (w << 3);
    float4 a = *(const float4*)qp;
    float4 c = *(const float4*)(qp + 4);
    qr[mt][0] = (f16)a.x; qr[mt][1] = (f16)a.y;
    qr[mt][2] = (f16)a.z; qr[mt][3] = (f16)a.w;
    qr[mt][4] = (f16)c.x; qr[mt][5] = (f16)c.y;
    qr[mt][6] = (f16)c.z; qr[mt][7] = (f16)c.w;
  }

  f32x16 acc[4];
#pragma unroll
  for (int mt = 0; mt < 4; ++mt)
#pragma unroll
    for (int r = 0; r < 16; ++r) acc[mt][r] = 0.f;

  f16x8 Wr[8], xfA[4], xfB[4];

  // ic-stagger: same-XCD blocks start at 8 phases
  const int icoff = (mb & 7) << 1;  // even

  // prologue: ring for ic=icoff, x frags for icoff
#pragma unroll
  for (int dd = 0; dd < 8; ++dd)
    Wr[dd] = *(const f16x8*)(wl + (((size_t)((dd << 4) + icoff)) << 10));
  LOADX4(xfA, icoff);

  for (int s2 = 0; s2 < 8; ++s2) {
    const int icO = (icoff + (s2 << 1) + 1) & 15;  // odd position
    const int icE = (icoff + (s2 << 1) + 2) & 15;  // next even position
    LOADX4(xfB, icO);
    DPASS(xfA, icO);   // consume even ic, prefetch odd into ring
    LOADX4(xfA, icE);  // s2==7: dummy reload (unused)
    DPASS(xfB, icE);   // consume odd, prefetch next even (s2==7: dead wrap)
  }

  // bias (wave 7 only): 4 chunks over QDIM, A = q-frag, B = Bt
  if (w == 7) {
#pragma unroll
    for (int kc = 0; kc < 4; ++kc) {
      f16x8 bf = *(const f16x8*)((const char*)Bt +
          (((size_t)nc * 4 + kc) << 10) + (hf << 9) + (l31 << 4));
#pragma unroll
      for (int mt = 0; mt < 4; ++mt) {
        f16x8 qf;
        XFRAG(qf, Q + (size_t)((mb << 7) + (mt << 5) + l31) * QDIM +
                  (kc << 4) + (hf << 3));
        acc[mt] = __builtin_amdgcn_mfma_f32_32x32x16_f16(qf, bf, acc[mt], 0, 0, 0);
      }
    }
  }

  // ---- two-phase 8-way d-reduction in LDS ----
  // C/D (32x32): col = lane&31, row = (reg&3) + 8*(reg>>2) + 4*(lane>>5)
  if (w < 4) {
#pragma unroll
    for (int mt = 0; mt < 4; ++mt)
#pragma unroll
      for (int r = 0; r < 16; ++r) {
        const int row = (mt << 5) + (r & 3) + ((r >> 2) << 3) + (hf << 2);
        red[w][row][l31] = acc[mt][r];
      }
  }
  __syncthreads();
  if (w >= 4) {
#pragma unroll
    for (int mt = 0; mt < 4; ++mt)
#pragma unroll
      for (int r = 0; r < 16; ++r) {
        const int row = (mt << 5) + (r & 3) + ((r >> 2) << 3) + (hf << 2);
        red[w - 4][row][l31] += acc[mt][r];
      }
  }
  __syncthreads();

  // final: 512 threads x 8 outputs; sum the 4 regions
  const int r = t >> 2;         // 0..127
  const int c0 = (t & 3) << 3;  // 0,8,16,24
  float s[8];
#pragma unroll
  for (int j = 0; j < 8; ++j) s[j] = 0.f;
#pragma unroll
  for (int j = 0; j < 4; ++j) {
    const float* rp = &red[j][r][c0];
    float4 v0 = *(const float4*)rp;
    float4 v1 = *(const float4*)(rp + 4);
    s[0] += v0.x; s[1] += v0.y; s[2] += v0.z; s[3] += v0.w;
    s[4] += v1.x; s[5] += v1.y; s[6] += v1.z; s[7] += v1.w;
  }
  float4 o0 = {s[0], s[1], s[2], s[3]};
  float4 o1 = {s[4], s[5], s[6], s[7]};
  float* op = out + ((size_t)((mb << 7) + r)) * 256 + (nc << 5) + c0;
  *(float4*)op = o0;
  *(float4*)(op + 4) = o1;
}

extern "C" void kernel_launch(void* const* d_in, const int* in_sizes, int n_in,
                              void* d_out, int out_size, void* d_ws, size_t ws_size,
                              hipStream_t stream) {
  (void)in_sizes; (void)n_in; (void)out_size; (void)ws_size;
  const float* x  = (const float*)d_in[0];   // [4096,256]
  const float* q  = (const float*)d_in[1];   // [4096,64]
  const float* W1 = (const float*)d_in[2];   // [64,256,256]
  const float* b1 = (const float*)d_in[3];   // [64,256]
  float* out = (float*)d_out;                // [4096,256] fp32

  // ws: Wt 8 MB | Bt 32 KB | Xt 2 MB  (~10.03 MB)
  f16* Wt = (f16*)d_ws;
  f16* Bt = (f16*)((char*)d_ws + ((size_t)8 << 20));
  f16* Xt = (f16*)((char*)d_ws + ((size_t)8 << 20) + 32768);

  prep<<<577, 256, 0, stream>>>(W1, b1, x, Wt, Xt, Bt);
  mlp_main<<<256, 512, 0, stream>>>(q, Wt, Xt, Bt, out);
}